// Round 1
// baseline (103.082 us; speedup 1.0000x reference)
//
#include <hip/hip_runtime.h>
#include <stdint.h>

// Problem geometry: inputs (32, 56, 56, 256) f32, n = 48 (k-th largest per row).
#define ROWS 32
#define ROW_LEN 802816      // 56*56*256
#define ROW_LEN4 200704     // ROW_LEN / 4
#define BPR 98              // blocks per row (200704 = 98 * 2048)
#define F4_PER_BLOCK 2048
#define THREADS 256
#define F4_PER_THREAD 8     // 2048 / 256
#define NBINS 2048          // top 11 bits of monotone key
#define CAND_CAP 2048

// ws layout (bytes):
//   hist : u32[ROWS][NBINS]             @ 0        (262144)
//   meta : i32[ROWS][4] {b0,cnt_gt,cnt} @ 262144   (512)
//   thr  : f32[ROWS]                    @ 262656   (128)
//   cand : u32[ROWS][CAND_CAP]          @ 262784   (262144)
#define OFF_META 262144
#define OFF_THR  262656
#define OFF_CAND 262784
#define ZERO_BYTES 262656   // hist + meta must be zeroed every call

// Monotone order-preserving f32 -> u32 key (larger float -> larger key).
__device__ __forceinline__ uint32_t fkey(float x) {
    uint32_t u = __float_as_uint(x);
    return (u & 0x80000000u) ? ~u : (u | 0x80000000u);
}

__global__ __launch_bounds__(THREADS) void k_hist(const float* __restrict__ in,
                                                  uint32_t* __restrict__ hist) {
    __shared__ uint32_t lh[NBINS];
    const int row = blockIdx.x / BPR;
    const int blk = blockIdx.x % BPR;
    for (int i = threadIdx.x; i < NBINS; i += THREADS) lh[i] = 0;
    __syncthreads();
    const float4* p = (const float4*)in + (size_t)row * ROW_LEN4
                      + (size_t)blk * F4_PER_BLOCK + threadIdx.x;
#pragma unroll
    for (int v = 0; v < F4_PER_THREAD; ++v) {
        float4 d = p[v * THREADS];
        atomicAdd(&lh[fkey(d.x) >> 21], 1u);
        atomicAdd(&lh[fkey(d.y) >> 21], 1u);
        atomicAdd(&lh[fkey(d.z) >> 21], 1u);
        atomicAdd(&lh[fkey(d.w) >> 21], 1u);
    }
    __syncthreads();
    uint32_t* gh = hist + (size_t)row * NBINS;
    for (int i = threadIdx.x; i < NBINS; i += THREADS) {
        uint32_t c = lh[i];
        if (c) atomicAdd(&gh[i], c);
    }
}

__global__ __launch_bounds__(THREADS) void k_findbin(const uint32_t* __restrict__ hist,
                                                     const int* __restrict__ n_ptr,
                                                     int* __restrict__ meta) {
    const int row = blockIdx.x;
    const uint32_t n = (uint32_t)(*n_ptr);
    __shared__ uint32_t part[THREADS];
    const uint32_t* gh = hist + (size_t)row * NBINS;
    // thread t sums a descending chunk of 8 bins
    uint32_t s = 0;
    const int hi = NBINS - 1 - threadIdx.x * 8;
    for (int j = 0; j < 8; ++j) s += gh[hi - j];
    part[threadIdx.x] = s;
    __syncthreads();
    if (threadIdx.x == 0) {
        uint32_t cum = 0;
        int b0 = 0; uint32_t cnt_gt = 0;
        for (int t = 0; t < THREADS; ++t) {
            if (cum + part[t] >= n) {
                const int h = NBINS - 1 - t * 8;
                for (int j = 0; j < 8; ++j) {
                    uint32_t c = gh[h - j];
                    if (cum + c >= n) { b0 = h - j; cnt_gt = cum; break; }
                    cum += c;
                }
                break;
            }
            cum += part[t];
        }
        meta[row * 4 + 0] = b0;
        meta[row * 4 + 1] = (int)cnt_gt;
    }
}

__global__ __launch_bounds__(THREADS) void k_compact(const float* __restrict__ in,
                                                     int* __restrict__ meta,
                                                     uint32_t* __restrict__ cand) {
    const int row = blockIdx.x / BPR;
    const int blk = blockIdx.x % BPR;
    const uint32_t b0 = (uint32_t)meta[row * 4 + 0];
    const float4* p = (const float4*)in + (size_t)row * ROW_LEN4
                      + (size_t)blk * F4_PER_BLOCK + threadIdx.x;
    uint32_t* rc = cand + (size_t)row * CAND_CAP;
    int* cnt = &meta[row * 4 + 2];
#pragma unroll
    for (int v = 0; v < F4_PER_THREAD; ++v) {
        float4 d = p[v * THREADS];
        uint32_t k0 = fkey(d.x), k1 = fkey(d.y), k2 = fkey(d.z), k3 = fkey(d.w);
        if ((k0 >> 21) == b0) { int pos = atomicAdd(cnt, 1); if (pos < CAND_CAP) rc[pos] = k0; }
        if ((k1 >> 21) == b0) { int pos = atomicAdd(cnt, 1); if (pos < CAND_CAP) rc[pos] = k1; }
        if ((k2 >> 21) == b0) { int pos = atomicAdd(cnt, 1); if (pos < CAND_CAP) rc[pos] = k2; }
        if ((k3 >> 21) == b0) { int pos = atomicAdd(cnt, 1); if (pos < CAND_CAP) rc[pos] = k3; }
    }
}

__global__ __launch_bounds__(THREADS) void k_select(const int* __restrict__ n_ptr,
                                                    const int* __restrict__ meta,
                                                    const uint32_t* __restrict__ cand,
                                                    float* __restrict__ thr) {
    const int row = blockIdx.x;
    __shared__ uint32_t h[256];
    __shared__ uint32_t sel, srank;
    const int n = *n_ptr;
    const int cnt_gt = meta[row * 4 + 1];
    int m = meta[row * 4 + 2];
    if (m > CAND_CAP) m = CAND_CAP;
    const uint32_t* rc = cand + (size_t)row * CAND_CAP;
    int r = n - cnt_gt;           // 1-indexed rank among candidates (from largest)
    if (r < 1) r = 1;

    uint32_t mask = 0xFFE00000u;  // top 11 bits fixed by compaction
    uint32_t prefix = ((uint32_t)meta[row * 4 + 0]) << 21;
    const int shifts[3] = {13, 5, 0};
    const int widths[3] = {256, 256, 32};
    for (int rd = 0; rd < 3; ++rd) {
        const int s = shifts[rd], W = widths[rd];
        for (int i = threadIdx.x; i < W; i += THREADS) h[i] = 0;
        __syncthreads();
        for (int i = threadIdx.x; i < m; i += THREADS) {
            uint32_t k = rc[i];
            if ((k & mask) == prefix) atomicAdd(&h[(k >> s) & (uint32_t)(W - 1)], 1u);
        }
        __syncthreads();
        if (threadIdx.x == 0) {
            uint32_t cum = 0; int v = 0;
            for (int d = W - 1; d >= 0; --d) {
                uint32_t c = h[d];
                if ((int)(cum + c) >= r) { v = d; break; }
                cum += c;
            }
            sel = (uint32_t)v; srank = (uint32_t)(r - (int)cum);
        }
        __syncthreads();
        prefix |= sel << s;
        mask |= (uint32_t)(W - 1) << s;
        r = (int)srank;
    }
    if (threadIdx.x == 0) {
        uint32_t k = prefix;
        uint32_t u = (k & 0x80000000u) ? (k & 0x7FFFFFFFu) : ~k;
        thr[row] = __uint_as_float(u);
    }
}

__global__ __launch_bounds__(THREADS) void k_mask(const float* __restrict__ in,
                                                  const float* __restrict__ thr,
                                                  float* __restrict__ out) {
    const int row = blockIdx.x / BPR;
    const int blk = blockIdx.x % BPR;
    const float t = thr[row];
    const size_t base = (size_t)row * ROW_LEN4 + (size_t)blk * F4_PER_BLOCK + threadIdx.x;
    const float4* p = (const float4*)in + base;
    float4* q = (float4*)out + base;
#pragma unroll
    for (int v = 0; v < F4_PER_THREAD; ++v) {
        float4 d = p[v * THREADS];
        d.x = (d.x >= t) ? d.x : 0.0f;
        d.y = (d.y >= t) ? d.y : 0.0f;
        d.z = (d.z >= t) ? d.z : 0.0f;
        d.w = (d.w >= t) ? d.w : 0.0f;
        q[v * THREADS] = d;
    }
}

extern "C" void kernel_launch(void* const* d_in, const int* in_sizes, int n_in,
                              void* d_out, int out_size, void* d_ws, size_t ws_size,
                              hipStream_t stream) {
    const float* in = (const float*)d_in[0];
    const int* n_ptr = (const int*)d_in[1];
    float* out = (float*)d_out;
    char* ws = (char*)d_ws;

    uint32_t* hist = (uint32_t*)ws;
    int* meta = (int*)(ws + OFF_META);
    float* thr = (float*)(ws + OFF_THR);
    uint32_t* cand = (uint32_t*)(ws + OFF_CAND);

    hipMemsetAsync(ws, 0, ZERO_BYTES, stream);
    k_hist<<<ROWS * BPR, THREADS, 0, stream>>>(in, hist);
    k_findbin<<<ROWS, THREADS, 0, stream>>>(hist, n_ptr, meta);
    k_compact<<<ROWS * BPR, THREADS, 0, stream>>>(in, meta, cand);
    k_select<<<ROWS, THREADS, 0, stream>>>(n_ptr, meta, cand, thr);
    k_mask<<<ROWS * BPR, THREADS, 0, stream>>>(in, thr, out);
}